// Round 1
// baseline (481.243 us; speedup 1.0000x reference)
//
#include <hip/hip_runtime.h>
#include <math.h>

// Problem: B=2, C=32, H=80, W=80, D=80, fp32.
// out = PERM^-1( softmax( Q@K^T ) @ V ) where Q/K/V are PERM'd+flattened views.
// Key fact: slice (b,c,h) of any input is a CONTIGUOUS [80][80] (w,d) block.
// S[b,w,v] = sum over all 2560 slices of X[w][:]·Xt[v][:]  (Gram over K=204800)

#define BB 2
#define CC 32
#define HH 80
#define WW 80
#define DD 80
#define CH (CC*HH)        // 2560 slices per batch
#define SLICE (WW*DD)     // 6400 floats, contiguous per (b,c,h)
#define PAD 84            // LDS row pad: 84 floats = 336B, 16B-aligned rows, conflict-free

// ---------------- QK: partial Gram per 5-slice chunk, atomic reduce ----------
__global__ __launch_bounds__(256, 2)
void qk_kernel(const float* __restrict__ x, const float* __restrict__ xt,
               float* __restrict__ S) {
  __shared__ __align__(16) float Xs[WW][PAD];
  __shared__ __align__(16) float Ts[WW][PAD];
  const int blk = blockIdx.x;        // 0..1023
  const int b = blk >> 9;            // 512 chunks per batch
  const int chunk = blk & 511;
  const int tid = threadIdx.x;
  const int ty = tid >> 4, tx = tid & 15;

  float acc[5][5] = {};
  const long base = (long)(b * CH + chunk * 5) * SLICE;

  for (int s = 0; s < 5; ++s) {
    const float* px = x  + base + (long)s * SLICE;
    const float* pt = xt + base + (long)s * SLICE;
    __syncthreads();                 // protect prior iter's LDS reads
    for (int i = tid; i < SLICE; i += 256) {
      int w = i / DD, d = i - w * DD;
      Xs[w][d] = px[i];
      Ts[w][d] = pt[i];
    }
    __syncthreads();
    for (int d = 0; d < DD; d += 4) {
      float a[5][4], t[5][4];
      #pragma unroll
      for (int i = 0; i < 5; ++i) {
        float4 v4 = *(const float4*)&Xs[ty + 16 * i][d];
        a[i][0] = v4.x; a[i][1] = v4.y; a[i][2] = v4.z; a[i][3] = v4.w;
      }
      #pragma unroll
      for (int j = 0; j < 5; ++j) {
        float4 v4 = *(const float4*)&Ts[tx + 16 * j][d];
        t[j][0] = v4.x; t[j][1] = v4.y; t[j][2] = v4.z; t[j][3] = v4.w;
      }
      #pragma unroll
      for (int r = 0; r < 4; ++r)
        #pragma unroll
        for (int i = 0; i < 5; ++i)
          #pragma unroll
          for (int j = 0; j < 5; ++j)
            acc[i][j] = fmaf(a[i][r], t[j][r], acc[i][j]);
    }
  }

  float* Sb = S + b * WW * WW;
  #pragma unroll
  for (int i = 0; i < 5; ++i)
    #pragma unroll
    for (int j = 0; j < 5; ++j)
      atomicAdd(&Sb[(ty + 16 * i) * WW + tx + 16 * j], acc[i][j]);
}

// ---------------- softmax over v, in place; one wave per row ----------------
__global__ void softmax_kernel(float* __restrict__ S) {
  const int r = blockIdx.x;          // 0..159  (b*80 + w)
  const int lane = threadIdx.x;      // 0..63
  float* row = S + r * WW;
  float v0 = (lane < WW) ? row[lane] : -INFINITY;
  float v1 = (lane + 64 < WW) ? row[lane + 64] : -INFINITY;
  float m = fmaxf(v0, v1);
  #pragma unroll
  for (int off = 32; off; off >>= 1) m = fmaxf(m, __shfl_xor(m, off));
  float e0 = (lane < WW) ? expf(v0 - m) : 0.f;
  float e1 = (lane + 64 < WW) ? expf(v1 - m) : 0.f;
  float ssum = e0 + e1;
  #pragma unroll
  for (int off = 32; off; off >>= 1) ssum += __shfl_xor(ssum, off);
  float inv = 1.f / ssum;
  if (lane < WW) row[lane] = e0 * inv;
  if (lane + 64 < WW) row[lane + 64] = e1 * inv;
}

// ---------------- PV: out_slice = att_b (80x80) @ g_slice (80x80) -----------
__global__ __launch_bounds__(256, 2)
void pv_kernel(const float* __restrict__ g, const float* __restrict__ att,
               float* __restrict__ out) {
  __shared__ __align__(16) float As[WW][PAD];   // att[w][v]
  __shared__ __align__(16) float Gs[WW][PAD];   // g[v][d]
  const int blk = blockIdx.x;        // 0..2559, 2 slices each
  const int tid = threadIdx.x;
  const int ty = tid >> 4, tx = tid & 15;
  const int s0 = blk * 2;
  const int b = s0 / CH;

  const float* ab = att + b * WW * WW;
  for (int i = tid; i < WW * WW; i += 256) {
    int w = i / WW;
    As[w][i - w * WW] = ab[i];
  }

  for (int s = 0; s < 2; ++s) {
    const long base = (long)(s0 + s) * SLICE;
    const float* pg = g + base;
    __syncthreads();                 // also covers As staging on s==0
    for (int i = tid; i < SLICE; i += 256) {
      int w = i / DD;
      Gs[w][i - w * DD] = pg[i];
    }
    __syncthreads();

    float acc[5][5] = {};
    for (int v = 0; v < WW; v += 4) {
      float a[5][4];
      #pragma unroll
      for (int i = 0; i < 5; ++i) {
        float4 v4 = *(const float4*)&As[ty + 16 * i][v];
        a[i][0] = v4.x; a[i][1] = v4.y; a[i][2] = v4.z; a[i][3] = v4.w;
      }
      #pragma unroll
      for (int r = 0; r < 4; ++r) {
        float gv[5];
        #pragma unroll
        for (int j = 0; j < 5; ++j) gv[j] = Gs[v + r][tx + 16 * j];
        #pragma unroll
        for (int i = 0; i < 5; ++i)
          #pragma unroll
          for (int j = 0; j < 5; ++j)
            acc[i][j] = fmaf(a[i][r], gv[j], acc[i][j]);
      }
    }

    float* po = out + base;
    #pragma unroll
    for (int i = 0; i < 5; ++i)
      #pragma unroll
      for (int j = 0; j < 5; ++j)
        po[(ty + 16 * i) * DD + tx + 16 * j] = acc[i][j];
  }
}

extern "C" void kernel_launch(void* const* d_in, const int* in_sizes, int n_in,
                              void* d_out, int out_size, void* d_ws, size_t ws_size,
                              hipStream_t stream) {
  const float* x_  = (const float*)d_in[0];
  const float* x_t = (const float*)d_in[1];
  const float* g_x = (const float*)d_in[2];
  float* out = (float*)d_out;
  float* S = (float*)d_ws;                    // 2*80*80 fp32 = 51.2 KB

  hipMemsetAsync(S, 0, BB * WW * WW * sizeof(float), stream);
  qk_kernel<<<dim3(1024), dim3(256), 0, stream>>>(x_, x_t, S);
  softmax_kernel<<<dim3(BB * WW), dim3(64), 0, stream>>>(S);
  pv_kernel<<<dim3(2560), dim3(256), 0, stream>>>(g_x, S, out);
}